// Round 4
// baseline (143.002 us; speedup 1.0000x reference)
//
#include <hip/hip_runtime.h>
#include <hip/hip_bf16.h>

#define IMG 64
#define NPTS 300
#define GRIDN 16
#define BATCH 8

typedef __hip_bfloat16 bf16;

__device__ __forceinline__ float sigm(float x) { return 1.0f / (1.0f + __expf(-x)); }
__device__ __forceinline__ float lo_bf(unsigned u) { return __uint_as_float(u << 16); }
__device__ __forceinline__ float hi_bf(unsigned u) { return __uint_as_float(u & 0xffff0000u); }
__device__ __forceinline__ float us_bf(unsigned short u) {
    return __uint_as_float(((unsigned)u) << 16);
}
__device__ __forceinline__ unsigned pack_bf2(float lo, float hi) {
    bf16 l = __float2bfloat16(lo), h = __float2bfloat16(hi);
    unsigned short ul = *(unsigned short*)&l, uh = *(unsigned short*)&h;
    return (unsigned)ul | ((unsigned)uh << 16);
}

template <typename T>
__device__ __forceinline__ float ldv(const void* p, int i);
template <>
__device__ __forceinline__ float ldv<float>(const void* p, int i) { return ((const float*)p)[i]; }
template <>
__device__ __forceinline__ float ldv<bf16>(const void* p, int i) {
    return __bfloat162float(((const bf16*)p)[i]);
}

// Dtype sniffer (run by first wave of a block): first 1800 bf16 slots of W1 (3600 B = full
// bf16 buffer, half the fp32 one -> in-bounds either way). bf16 W1 ~ U(+-0.183) => max ~0.18;
// fp32 storage read as bf16 has random half-words => max >> 4 whp.  Returns via LDS.
__device__ __forceinline__ void sniff(const void* W1, int* sflag, int t) {
    if (t < 64) {
        float m = 0.0f;
        for (int i = t; i < 1800; i += 64) {
            float v = fabsf(__bfloat162float(((const bf16*)W1)[i]));
            if (!(v < 1e30f)) v = 1e30f;
            m = fmaxf(m, v);
        }
#pragma unroll
        for (int d = 1; d < 64; d <<= 1) m = fmaxf(m, __shfl_xor(m, d));
        if (t == 0) *sflag = (m > 4.0f) ? 1 : 0;
    }
}

// ---------------- K1: fused tiny-MLP + K-split partial GEMM ----------------
// grid (64 jblocks, 4 kslices) x 256 thr. Each block redundantly computes layer1 (full) and
// its 120-row slice of h2, then partial = h2_slice @ W3_slice for its 256 columns.
// partial[(ks*8+b)*16384 + col], fp32 (2 MB total).
template <typename T>
__device__ void prep_body(const void* zs, const void* W1, const void* b1, const void* W2,
                          const void* b2, const void* W3, float* __restrict__ partial) {
    __shared__ float z[BATCH][30];
    __shared__ float h1[BATCH][60];
    __shared__ float h2s[BATCH][120];
    int t = threadIdx.x;
    int jb = blockIdx.x;   // 0..63
    int ks = blockIdx.y;   // 0..3
    int base = ks * 120;

    if (t < 240) {
        int b = t / 30, i = t - b * 30;
        z[b][i] = ldv<T>(zs, t);
    }
    __syncthreads();
    for (int idx = t; idx < 480; idx += 256) {
        int b = idx / 60, j = idx - b * 60;
        float acc = ldv<T>(b1, j);
#pragma unroll
        for (int i = 0; i < 30; ++i) acc = fmaf(z[b][i], ldv<T>(W1, i * 60 + j), acc);
        h1[b][j] = sigm(acc);
    }
    __syncthreads();
    for (int idx = t; idx < 960; idx += 256) {
        int b = idx / 120, rr = idx - b * 120;
        int col = base + rr;
        float acc = ldv<T>(b2, col);
#pragma unroll
        for (int i = 0; i < 60; ++i) acc = fmaf(h1[b][i], ldv<T>(W2, i * 480 + col), acc);
        h2s[b][rr] = sigm(acc);
    }
    __syncthreads();

    int col = jb * 256 + t;
    float acc[BATCH];
#pragma unroll
    for (int b = 0; b < BATCH; ++b) acc[b] = 0.0f;
#pragma unroll 15
    for (int r = 0; r < 120; ++r) {
        int i = base + r;
        float w;
        if (sizeof(T) == 2)
            w = us_bf(((const unsigned short*)W3)[(size_t)i * 16384 + col]);
        else
            w = ((const float*)W3)[(size_t)i * 16384 + col];
#pragma unroll
        for (int b = 0; b < BATCH; ++b) acc[b] = fmaf(h2s[b][r], w, acc[b]);
    }
#pragma unroll
    for (int b = 0; b < BATCH; ++b)
        partial[(((size_t)ks * BATCH + b) << 14) + col] = acc[b];
}

__global__ __launch_bounds__(256) void prep_kernel(const void* zs, const void* W1,
                                                   const void* b1, const void* W2,
                                                   const void* b2, const void* W3,
                                                   float* __restrict__ partial) {
    __shared__ int sflag;
    int t = threadIdx.x;
    sniff(W1, &sflag, t);
    __syncthreads();
    if (sflag)
        prep_body<float>(zs, W1, b1, W2, b2, W3, partial);
    else
        prep_body<bf16>(zs, W1, b1, W2, b2, W3, partial);
}

// ---------------- K2: reduce partials -> LDS volume, then ray render ----------------
// 512 blocks x 256 thr. Block = 64 rays of one image (b = blockIdx/64). Stage: sum 4 partial
// slices + bias, sigmoid, pack 4x bf16 -> vox[4096] uint2 (32 KB LDS). Then render.
__global__ __launch_bounds__(256) void render_kernel(const void* W1, const void* b3,
                                                     const void* Rm, const void* Tm,
                                                     const float* __restrict__ partial,
                                                     void* out) {
    __shared__ uint2 vox[4096];
    __shared__ int sflag;
    int t = threadIdx.x;
    sniff(W1, &sflag, t);
    __syncthreads();
    int f32in = sflag;

    int rayBase = blockIdx.x * 64;
    int b = rayBase >> 12;

    // reduce: 16 voxels per thread, all 4 channels each
    for (int r = 0; r < 16; ++r) {
        int v = r * 256 + t;
        float s[4];
#pragma unroll
        for (int c = 0; c < 4; ++c) {
            int j = (c << 12) + v;
            float a = f32in ? ((const float*)b3)[j] : us_bf(((const unsigned short*)b3)[j]);
#pragma unroll
            for (int ks = 0; ks < 4; ++ks)
                a += partial[(((size_t)ks * BATCH + b) << 14) + j];
            s[c] = sigm(a);
        }
        vox[v] = make_uint2(pack_bf2(s[0], s[1]), pack_bf2(s[2], s[3]));
    }
    __syncthreads();

    int ray = rayBase + (t >> 2);
    int seg = t & 3;
    int pix = ray & 4095;
    int h = pix >> 6, w = pix & 63;

    const float inv_f = 0.57735026919f;  // tan(30deg)
    float dcx = (0.984375f - 0.03125f * (float)w) * inv_f;
    float dcy = (0.984375f - 0.03125f * (float)h) * inv_f;

    float R[9], Tv[3];
    if (f32in) {
#pragma unroll
        for (int i = 0; i < 9; ++i) R[i] = ((const float*)Rm)[b * 9 + i];
#pragma unroll
        for (int i = 0; i < 3; ++i) Tv[i] = ((const float*)Tm)[b * 3 + i];
    } else {
#pragma unroll
        for (int i = 0; i < 9; ++i) R[i] = __bfloat162float(((const bf16*)Rm)[b * 9 + i]);
#pragma unroll
        for (int i = 0; i < 3; ++i) Tv[i] = __bfloat162float(((const bf16*)Tm)[b * 3 + i]);
    }

    float dx_ = dcx * R[0] + dcy * R[1] + R[2];
    float dy_ = dcx * R[3] + dcy * R[4] + R[5];
    float dz_ = dcx * R[6] + dcy * R[7] + R[8];
    float ox = -(Tv[0] * R[0] + Tv[1] * R[1] + Tv[2] * R[2]);
    float oy = -(Tv[0] * R[3] + Tv[1] * R[4] + Tv[2] * R[5]);
    float oz = -(Tv[0] * R[6] + Tv[1] * R[7] + Tv[2] * R[8]);

    // slab: contribution possible only while |world coord| < 0.85 on every axis
    // (ix = p*10+7.5 in (-1,16) <=> |p| < 0.85)
    float tA = -1e30f, tB = 1e30f;
    bool miss = false;
    {
        float dd[3] = {dx_, dy_, dz_}, oo[3] = {ox, oy, oz};
#pragma unroll
        for (int a = 0; a < 3; ++a) {
            if (fabsf(dd[a]) > 1e-8f) {
                float inv = 1.0f / dd[a];
                float ra = (-0.85f - oo[a]) * inv, rb = (0.85f - oo[a]) * inv;
                tA = fmaxf(tA, fminf(ra, rb));
                tB = fminf(tB, fmaxf(ra, rb));
            } else if (fabsf(oo[a]) >= 0.85f) {
                miss = true;
            }
        }
    }
    const float step = 2.9f / 299.0f;
    const float inv_step = 299.0f / 2.9f;
    int ilo = 0, ihi = -1;
    if (!miss && tB > tA) {
        float flo = fmaxf(-2.0f, fminf(302.0f, ceilf((tA - 0.1f) * inv_step)));
        float fhi = fmaxf(-2.0f, fminf(302.0f, floorf((tB - 0.1f) * inv_step)));
        ilo = (int)flo - 1;  // widen 1 step each side; out-of-grid samples contribute exactly 0
        ihi = (int)fhi + 1;
        if (ilo < 0) ilo = 0;
        if (ihi > 299) ihi = 299;
    }
    int n = ihi - ilo + 1;
    if (n < 0) n = 0;
    int s0 = ilo + (n * seg) / 4;
    int s1 = ilo + (n * (seg + 1)) / 4;

    float cr = 0.f, cg = 0.f, cb = 0.f, Pa = 1.f;
    for (int i = s0; i < s1; ++i) {
        float tt = 0.1f + step * (float)i;
        float ix = fmaf(fmaf(tt, dx_, ox), 10.0f, 7.5f);
        float iy = fmaf(fmaf(tt, dy_, oy), 10.0f, 7.5f);
        float iz = fmaf(fmaf(tt, dz_, oz), 10.0f, 7.5f);
        float fx = floorf(ix), fy = floorf(iy), fz = floorf(iz);
        float txf = ix - fx, tyf = iy - fy, tzf = iz - fz;
        int x0 = (int)fx, y0 = (int)fy, z0 = (int)fz;
        float wx0 = (x0 >= 0 && x0 <= 15) ? (1.0f - txf) : 0.0f;
        float wx1 = (x0 >= -1 && x0 <= 14) ? txf : 0.0f;
        float wy0 = (y0 >= 0 && y0 <= 15) ? (1.0f - tyf) : 0.0f;
        float wy1 = (y0 >= -1 && y0 <= 14) ? tyf : 0.0f;
        float wz0 = (z0 >= 0 && z0 <= 15) ? (1.0f - tzf) : 0.0f;
        float wz1 = (z0 >= -1 && z0 <= 14) ? tzf : 0.0f;
        int xi0 = min(max(x0, 0), 15), xi1 = min(max(x0 + 1, 0), 15);
        int yi0 = min(max(y0, 0), 15), yi1 = min(max(y0 + 1, 0), 15);
        int zi0 = min(max(z0, 0), 15), zi1 = min(max(z0 + 1, 0), 15);

        float sx = 0.f, sr = 0.f, sg = 0.f, sb = 0.f;
#define CORN(W, ZI, YI, XI)                              \
    {                                                    \
        uint2 q = vox[((ZI) << 8) + ((YI) << 4) + (XI)]; \
        sx = fmaf((W), lo_bf(q.x), sx);                  \
        sr = fmaf((W), hi_bf(q.x), sr);                  \
        sg = fmaf((W), lo_bf(q.y), sg);                  \
        sb = fmaf((W), hi_bf(q.y), sb);                  \
    }
        float wxy00 = wx0 * wy0, wxy10 = wx1 * wy0, wxy01 = wx0 * wy1, wxy11 = wx1 * wy1;
        CORN(wxy00 * wz0, zi0, yi0, xi0)
        CORN(wxy10 * wz0, zi0, yi0, xi1)
        CORN(wxy01 * wz0, zi0, yi1, xi0)
        CORN(wxy11 * wz0, zi0, yi1, xi1)
        CORN(wxy00 * wz1, zi1, yi0, xi0)
        CORN(wxy10 * wz1, zi1, yi0, xi1)
        CORN(wxy01 * wz1, zi1, yi1, xi0)
        CORN(wxy11 * wz1, zi1, yi1, xi1)
#undef CORN

        float wgt = sx * Pa;
        cr = fmaf(wgt, sr, cr);
        cg = fmaf(wgt, sg, cg);
        cb = fmaf(wgt, sb, cb);
        Pa *= (1.0f - sx);  // 1+1e-10-sx: the 1e-10 vanishes in fp32; opacity prod identical
    }

    // compose the 4 depth segments (ordered) within each 4-lane group
#pragma unroll
    for (int d = 1; d < 4; d <<= 1) {
        float o_cr = __shfl_xor(cr, d);
        float o_cg = __shfl_xor(cg, d);
        float o_cb = __shfl_xor(cb, d);
        float o_Pa = __shfl_xor(Pa, d);
        bool first = ((seg & d) == 0);
        cr = first ? fmaf(Pa, o_cr, cr) : fmaf(o_Pa, cr, o_cr);
        cg = first ? fmaf(Pa, o_cg, cg) : fmaf(o_Pa, cg, o_cg);
        cb = first ? fmaf(Pa, o_cb, cb) : fmaf(o_Pa, cb, o_cb);
        Pa *= o_Pa;
    }

    if (seg == 0) {
        if (f32in) {
            float* of = (float*)out;
            of[ray] = 1.0f - Pa;
            float* orgb = of + BATCH * IMG * IMG;
            orgb[ray * 3 + 0] = cr;
            orgb[ray * 3 + 1] = cg;
            orgb[ray * 3 + 2] = cb;
        } else {
            bf16* ob = (bf16*)out;
            ob[ray] = __float2bfloat16(1.0f - Pa);
            bf16* orgb = ob + BATCH * IMG * IMG;
            orgb[ray * 3 + 0] = __float2bfloat16(cr);
            orgb[ray * 3 + 1] = __float2bfloat16(cg);
            orgb[ray * 3 + 2] = __float2bfloat16(cb);
        }
    }
}

extern "C" void kernel_launch(void* const* d_in, const int* in_sizes, int n_in,
                              void* d_out, int out_size, void* d_ws, size_t ws_size,
                              hipStream_t stream) {
    const void* zs = d_in[0];
    const void* W1 = d_in[1];
    const void* b1 = d_in[2];
    const void* W2 = d_in[3];
    const void* b2 = d_in[4];
    const void* W3 = d_in[5];
    const void* b3 = d_in[6];
    const void* Rm = d_in[7];
    const void* Tm = d_in[8];

    float* partial = (float*)d_ws;  // 4 slices x 8 batches x 16384 fp32 = 2 MB

    hipLaunchKernelGGL(prep_kernel, dim3(64, 4), dim3(256), 0, stream, zs, W1, b1, W2, b2, W3,
                       partial);
    hipLaunchKernelGGL(render_kernel, dim3(512), dim3(256), 0, stream, W1, b3, Rm, Tm, partial,
                       d_out);
}

// Round 5
// 123.464 us; speedup vs baseline: 1.1582x; 1.1582x over previous
//
#include <hip/hip_runtime.h>
#include <hip/hip_bf16.h>

#define IMG 64
#define NPTS 300
#define GRIDN 16
#define BATCH 8

typedef __hip_bfloat16 bf16;

__device__ __forceinline__ float sigm(float x) { return 1.0f / (1.0f + __expf(-x)); }
__device__ __forceinline__ float lo_bf(unsigned u) { return __uint_as_float(u << 16); }
__device__ __forceinline__ float hi_bf(unsigned u) { return __uint_as_float(u & 0xffff0000u); }
__device__ __forceinline__ float us_bf(unsigned short u) {
    return __uint_as_float(((unsigned)u) << 16);
}

template <typename T>
__device__ __forceinline__ float ldv(const void* p, int i);
template <>
__device__ __forceinline__ float ldv<float>(const void* p, int i) { return ((const float*)p)[i]; }
template <>
__device__ __forceinline__ float ldv<bf16>(const void* p, int i) {
    return __bfloat162float(((const bf16*)p)[i]);
}

// Dtype sniffer: first 1800 bf16 slots of W1 (3600 B = full bf16 buffer, half the fp32 one
// -> in-bounds either way). bf16 W1 ~ U(+-0.183) => max ~0.18; fp32 storage read as bf16 has
// random half-words => max >> 4 whp.
__device__ __forceinline__ void sniff(const void* W1, int* sflag, int t) {
    if (t < 64) {
        float m = 0.0f;
        for (int i = t; i < 1800; i += 64) {
            float v = fabsf(__bfloat162float(((const bf16*)W1)[i]));
            if (!(v < 1e30f)) v = 1e30f;
            m = fmaxf(m, v);
        }
#pragma unroll
        for (int d = 1; d < 64; d <<= 1) m = fmaxf(m, __shfl_xor(m, d));
        if (t == 0) *sflag = (m > 4.0f) ? 1 : 0;
    }
}

// ---------------- K1: fused tiny-MLP + K-split partial GEMM ----------------
// grid (16 jblocks, 16 kslices) x 256 thr — round-3's proven w3_partial core.
// Each block redundantly computes layer1 (full) + its 30-row h2 slice (~30k MACs, free),
// then partial = h2_slice @ W3_slice for its 1024 columns (4 cols/thread, ushort4 loads).
template <typename T>
__device__ void prep_body(const void* zs, const void* b1, const void* W1, const void* W2,
                          const void* b2, const void* W3, float* __restrict__ partial) {
    __shared__ float z[BATCH][30];
    __shared__ float h1[BATCH][60];
    __shared__ float h2s[BATCH][30];
    int t = threadIdx.x;
    int jb = blockIdx.x;  // 0..15 -> 1024 cols
    int s = blockIdx.y;   // 0..15 -> rows 30s..30s+29
    int i0 = s * 30;

    if (t < 240) {
        int b = t / 30, i = t - b * 30;
        z[b][i] = ldv<T>(zs, t);
    }
    __syncthreads();
    for (int idx = t; idx < 480; idx += 256) {
        int b = idx / 60, j = idx - b * 60;
        float acc = ldv<T>(b1, j);
#pragma unroll
        for (int i = 0; i < 30; ++i) acc = fmaf(z[b][i], ldv<T>(W1, i * 60 + j), acc);
        h1[b][j] = sigm(acc);
    }
    __syncthreads();
    if (t < 240) {
        int b = t / 30, rr = t - b * 30;
        int col = i0 + rr;
        float acc = ldv<T>(b2, col);
#pragma unroll
        for (int i = 0; i < 60; ++i) acc = fmaf(h1[b][i], ldv<T>(W2, i * 480 + col), acc);
        h2s[b][rr] = sigm(acc);
    }
    __syncthreads();

    int j0 = jb * 1024 + t * 4;
    float acc[BATCH][4];
#pragma unroll
    for (int b = 0; b < BATCH; ++b)
#pragma unroll
        for (int c = 0; c < 4; ++c) acc[b][c] = 0.0f;

#pragma unroll 6
    for (int i = 0; i < 30; ++i) {
        float w0, w1, w2, w3v;
        if (sizeof(T) == 2) {
            ushort4 q = *(const ushort4*)((const unsigned short*)W3 + (size_t)(i0 + i) * 16384 + j0);
            w0 = us_bf(q.x); w1 = us_bf(q.y); w2 = us_bf(q.z); w3v = us_bf(q.w);
        } else {
            float4 q = *(const float4*)((const float*)W3 + (size_t)(i0 + i) * 16384 + j0);
            w0 = q.x; w1 = q.y; w2 = q.z; w3v = q.w;
        }
#pragma unroll
        for (int b = 0; b < BATCH; ++b) {
            float h = h2s[b][i];
            acc[b][0] = fmaf(h, w0, acc[b][0]);
            acc[b][1] = fmaf(h, w1, acc[b][1]);
            acc[b][2] = fmaf(h, w2, acc[b][2]);
            acc[b][3] = fmaf(h, w3v, acc[b][3]);
        }
    }
#pragma unroll
    for (int b = 0; b < BATCH; ++b) {
        float4 st = {acc[b][0], acc[b][1], acc[b][2], acc[b][3]};
        *(float4*)(partial + ((size_t)(s * BATCH + b) << 14) + j0) = st;
    }
}

__global__ __launch_bounds__(256) void prep_kernel(const void* zs, const void* W1,
                                                   const void* b1, const void* W2,
                                                   const void* b2, const void* W3,
                                                   float* __restrict__ partial,
                                                   int* __restrict__ flag) {
    __shared__ int sflag;
    int t = threadIdx.x;
    sniff(W1, &sflag, t);
    __syncthreads();
    if (blockIdx.x == 0 && blockIdx.y == 0 && t == 0) *flag = sflag;
    if (sflag)
        prep_body<float>(zs, b1, W1, W2, b2, W3, partial);
    else
        prep_body<bf16>(zs, b1, W1, W2, b2, W3, partial);
}

// ---------------- K2: reduce 16 partials + bias -> sigmoid -> packed bf16 volume ----------
// (round-3 proven) 512 blocks x 256 thr; each partial element read exactly once (8 MB).
__global__ __launch_bounds__(256) void w3_reduce_kernel(const float* __restrict__ partial,
                                                        const void* b3, bf16* __restrict__ volbf,
                                                        const int* __restrict__ flag) {
    int tid = blockIdx.x * 256 + threadIdx.x;  // 131072 = 8 batches x 16384 cols
    int b = tid >> 14, j = tid & 16383;
    float a = 0.0f;
#pragma unroll
    for (int s = 0; s < 16; ++s) a += partial[((size_t)(s * BATCH + b) << 14) + j];
    a += (*flag) ? ldv<float>(b3, j) : ldv<bf16>(b3, j);
    a = sigm(a);
    int c = j >> 12, v = j & 4095;
    volbf[(size_t)((b << 12) + v) * 4 + c] = __float2bfloat16(a);
}

// ---------------- K3: ray render (round-3 proven) ----------------
// 512 blocks x 256 thr. Block = 64 rays of one image; lane = ray*4 + seg (4 depth segments).
// LDS: 4096 voxels x uint2 (4 packed bf16: sigma,r | g,b) = 32 KB.
__global__ __launch_bounds__(256) void render_kernel(const void* Rm, const void* Tm,
                                                     const bf16* __restrict__ volbf, void* out,
                                                     const int* __restrict__ flag) {
    __shared__ uint2 vox[4096];
    int t = threadIdx.x;
    int rayBase = blockIdx.x * 64;
    int b = rayBase >> 12;
    const uint2* src = (const uint2*)(volbf + (size_t)b * 4096 * 4);
    for (int i = t; i < 4096; i += 256) vox[i] = src[i];
    __syncthreads();

    int f32out = *flag;
    int ray = rayBase + (t >> 2);
    int seg = t & 3;
    int pix = ray & 4095;
    int h = pix >> 6, w = pix & 63;

    const float inv_f = 0.57735026919f;  // tan(30deg)
    float dcx = (0.984375f - 0.03125f * (float)w) * inv_f;
    float dcy = (0.984375f - 0.03125f * (float)h) * inv_f;

    float R[9], Tv[3];
    if (f32out) {
#pragma unroll
        for (int i = 0; i < 9; ++i) R[i] = ((const float*)Rm)[b * 9 + i];
#pragma unroll
        for (int i = 0; i < 3; ++i) Tv[i] = ((const float*)Tm)[b * 3 + i];
    } else {
#pragma unroll
        for (int i = 0; i < 9; ++i) R[i] = __bfloat162float(((const bf16*)Rm)[b * 9 + i]);
#pragma unroll
        for (int i = 0; i < 3; ++i) Tv[i] = __bfloat162float(((const bf16*)Tm)[b * 3 + i]);
    }

    float dx_ = dcx * R[0] + dcy * R[1] + R[2];
    float dy_ = dcx * R[3] + dcy * R[4] + R[5];
    float dz_ = dcx * R[6] + dcy * R[7] + R[8];
    float ox = -(Tv[0] * R[0] + Tv[1] * R[1] + Tv[2] * R[2]);
    float oy = -(Tv[0] * R[3] + Tv[1] * R[4] + Tv[2] * R[5]);
    float oz = -(Tv[0] * R[6] + Tv[1] * R[7] + Tv[2] * R[8]);

    // slab: contribution possible only while |world coord| < 0.85 on every axis
    // (ix = p*10+7.5 in (-1,16) <=> |p| < 0.85)
    float tA = -1e30f, tB = 1e30f;
    bool miss = false;
    {
        float dd[3] = {dx_, dy_, dz_}, oo[3] = {ox, oy, oz};
#pragma unroll
        for (int a = 0; a < 3; ++a) {
            if (fabsf(dd[a]) > 1e-8f) {
                float inv = 1.0f / dd[a];
                float ra = (-0.85f - oo[a]) * inv, rb = (0.85f - oo[a]) * inv;
                tA = fmaxf(tA, fminf(ra, rb));
                tB = fminf(tB, fmaxf(ra, rb));
            } else if (fabsf(oo[a]) >= 0.85f) {
                miss = true;
            }
        }
    }
    const float step = 2.9f / 299.0f;
    const float inv_step = 299.0f / 2.9f;
    int ilo = 0, ihi = -1;
    if (!miss && tB > tA) {
        float flo = fmaxf(-2.0f, fminf(302.0f, ceilf((tA - 0.1f) * inv_step)));
        float fhi = fmaxf(-2.0f, fminf(302.0f, floorf((tB - 0.1f) * inv_step)));
        ilo = (int)flo - 1;  // widen 1 step each side; out-of-grid samples contribute exactly 0
        ihi = (int)fhi + 1;
        if (ilo < 0) ilo = 0;
        if (ihi > 299) ihi = 299;
    }
    int n = ihi - ilo + 1;
    if (n < 0) n = 0;
    int s0 = ilo + (n * seg) / 4;
    int s1 = ilo + (n * (seg + 1)) / 4;

    float cr = 0.f, cg = 0.f, cb = 0.f, Pa = 1.f;
    for (int i = s0; i < s1; ++i) {
        float tt = 0.1f + step * (float)i;
        float ix = fmaf(fmaf(tt, dx_, ox), 10.0f, 7.5f);
        float iy = fmaf(fmaf(tt, dy_, oy), 10.0f, 7.5f);
        float iz = fmaf(fmaf(tt, dz_, oz), 10.0f, 7.5f);
        float fx = floorf(ix), fy = floorf(iy), fz = floorf(iz);
        float txf = ix - fx, tyf = iy - fy, tzf = iz - fz;
        int x0 = (int)fx, y0 = (int)fy, z0 = (int)fz;
        float wx0 = (x0 >= 0 && x0 <= 15) ? (1.0f - txf) : 0.0f;
        float wx1 = (x0 >= -1 && x0 <= 14) ? txf : 0.0f;
        float wy0 = (y0 >= 0 && y0 <= 15) ? (1.0f - tyf) : 0.0f;
        float wy1 = (y0 >= -1 && y0 <= 14) ? tyf : 0.0f;
        float wz0 = (z0 >= 0 && z0 <= 15) ? (1.0f - tzf) : 0.0f;
        float wz1 = (z0 >= -1 && z0 <= 14) ? tzf : 0.0f;
        int xi0 = min(max(x0, 0), 15), xi1 = min(max(x0 + 1, 0), 15);
        int yi0 = min(max(y0, 0), 15), yi1 = min(max(y0 + 1, 0), 15);
        int zi0 = min(max(z0, 0), 15), zi1 = min(max(z0 + 1, 0), 15);

        float sx = 0.f, sr = 0.f, sg = 0.f, sb = 0.f;
#define CORN(W, ZI, YI, XI)                              \
    {                                                    \
        uint2 q = vox[((ZI) << 8) + ((YI) << 4) + (XI)]; \
        sx = fmaf((W), lo_bf(q.x), sx);                  \
        sr = fmaf((W), hi_bf(q.x), sr);                  \
        sg = fmaf((W), lo_bf(q.y), sg);                  \
        sb = fmaf((W), hi_bf(q.y), sb);                  \
    }
        float wxy00 = wx0 * wy0, wxy10 = wx1 * wy0, wxy01 = wx0 * wy1, wxy11 = wx1 * wy1;
        CORN(wxy00 * wz0, zi0, yi0, xi0)
        CORN(wxy10 * wz0, zi0, yi0, xi1)
        CORN(wxy01 * wz0, zi0, yi1, xi0)
        CORN(wxy11 * wz0, zi0, yi1, xi1)
        CORN(wxy00 * wz1, zi1, yi0, xi0)
        CORN(wxy10 * wz1, zi1, yi0, xi1)
        CORN(wxy01 * wz1, zi1, yi1, xi0)
        CORN(wxy11 * wz1, zi1, yi1, xi1)
#undef CORN

        float wgt = sx * Pa;
        cr = fmaf(wgt, sr, cr);
        cg = fmaf(wgt, sg, cg);
        cb = fmaf(wgt, sb, cb);
        Pa *= (1.0f - sx);  // 1+1e-10-sx: the 1e-10 vanishes in fp32; opacity prod identical
    }

    // compose the 4 depth segments (ordered) within each 4-lane group
#pragma unroll
    for (int d = 1; d < 4; d <<= 1) {
        float o_cr = __shfl_xor(cr, d);
        float o_cg = __shfl_xor(cg, d);
        float o_cb = __shfl_xor(cb, d);
        float o_Pa = __shfl_xor(Pa, d);
        bool first = ((seg & d) == 0);
        cr = first ? fmaf(Pa, o_cr, cr) : fmaf(o_Pa, cr, o_cr);
        cg = first ? fmaf(Pa, o_cg, cg) : fmaf(o_Pa, cg, o_cg);
        cb = first ? fmaf(Pa, o_cb, cb) : fmaf(o_Pa, cb, o_cb);
        Pa *= o_Pa;
    }

    if (seg == 0) {
        if (f32out) {
            float* of = (float*)out;
            of[ray] = 1.0f - Pa;
            float* orgb = of + BATCH * IMG * IMG;
            orgb[ray * 3 + 0] = cr;
            orgb[ray * 3 + 1] = cg;
            orgb[ray * 3 + 2] = cb;
        } else {
            bf16* ob = (bf16*)out;
            ob[ray] = __float2bfloat16(1.0f - Pa);
            bf16* orgb = ob + BATCH * IMG * IMG;
            orgb[ray * 3 + 0] = __float2bfloat16(cr);
            orgb[ray * 3 + 1] = __float2bfloat16(cg);
            orgb[ray * 3 + 2] = __float2bfloat16(cb);
        }
    }
}

extern "C" void kernel_launch(void* const* d_in, const int* in_sizes, int n_in,
                              void* d_out, int out_size, void* d_ws, size_t ws_size,
                              hipStream_t stream) {
    const void* zs = d_in[0];
    const void* W1 = d_in[1];
    const void* b1 = d_in[2];
    const void* W2 = d_in[3];
    const void* b2 = d_in[4];
    const void* W3 = d_in[5];
    const void* b3 = d_in[6];
    const void* Rm = d_in[7];
    const void* Tm = d_in[8];

    // ws layout: volbf16 [0, 256K) | partial fp32 16x8x16384 [256K, 256K+8M) | flag
    bf16* volbf = (bf16*)d_ws;
    float* partial = (float*)((char*)d_ws + 262144);
    int* flag = (int*)((char*)d_ws + 262144 + (size_t)16 * BATCH * 16384 * 4);

    hipLaunchKernelGGL(prep_kernel, dim3(16, 16), dim3(256), 0, stream, zs, W1, b1, W2, b2, W3,
                       partial, flag);
    hipLaunchKernelGGL(w3_reduce_kernel, dim3(512), dim3(256), 0, stream, partial, b3, volbf,
                       flag);
    hipLaunchKernelGGL(render_kernel, dim3(512), dim3(256), 0, stream, Rm, Tm, volbf, d_out,
                       flag);
}